// Round 8
// baseline (287.489 us; speedup 1.0000x reference)
//
#include <hip/hip_runtime.h>
#include <math.h>

#define NEG_SLOPE 0.2f

typedef unsigned int uint;
typedef unsigned short ushort;
typedef __bf16 bf16x8 __attribute__((ext_vector_type(8)));
typedef float f32x4 __attribute__((ext_vector_type(4)));

__device__ __forceinline__ uint bf16r(float a) {
    uint u = __float_as_uint(a);
    return (u + 0x7fffu + ((u >> 16) & 1u)) >> 16;
}
__device__ __forceinline__ uint bf16pack(float a, float b) {
    return bf16r(a) | (bf16r(b) << 16);
}
__device__ __forceinline__ float bflo(uint u) { return __uint_as_float(u << 16); }
__device__ __forceinline__ float bfhi(uint u) { return __uint_as_float(u & 0xffff0000u); }

// ---------- prep: wbt, sw1t(perm), wsum=0, count/cursor=0 ----------
__global__ void prep_kernel(const float* __restrict__ fc0, const float* __restrict__ fc1,
                            const float* __restrict__ sw1, ushort* __restrict__ wbt,
                            ushort* __restrict__ sw1t, float* __restrict__ wsum,
                            int* __restrict__ count, int* __restrict__ cursor, int Ntot) {
    int b = blockIdx.x;
    if (b == 0 && threadIdx.x == 0) { wsum[0] = 0.f; wsum[1] = 0.f; }
    if (b < 256) {
        int idx = b * 256 + threadIdx.x;            // 65536
        const float* W = (idx >> 15) ? fc1 : fc0;
        int r = idx & 32767;
        int c = r >> 7, k = r & 127;
        wbt[idx] = (ushort)bf16r(W[(size_t)k * 256 + c]);
    } else if (b < 384) {
        int idx = (b - 256) * 256 + threadIdx.x;    // 32768
        int c = idx >> 8, p = idx & 255;
        int col = (p & ~63) + ((p & 3) * 16) + ((p >> 2) & 15);
        sw1t[idx] = (ushort)bf16r(sw1[(size_t)col * 128 + c]);
    } else {
        int i = (b - 384) * 256 + threadIdx.x;
        if (i < Ntot) { count[i] = 0; cursor[i] = 0; }
    }
}

// ---------- hist over both layers: d' = dst + l*N ----------
__global__ void hist_kernel(const int* __restrict__ e0, const int* __restrict__ e1,
                            int* __restrict__ count, int E, int N) {
    int e = blockIdx.x * blockDim.x + threadIdx.x;
    if (e >= 2 * E) return;
    int l = (e >= E);
    int ee = e - l * E;
    const int* edges = l ? e1 : e0;
    atomicAdd(&count[edges[E + ee] + l * N], 1);
}

__global__ void scan1_kernel(const int* __restrict__ count, int* __restrict__ base,
                             int* __restrict__ bsum, int Ntot) {
    __shared__ int ws_s[4];
    int b = blockIdx.x;
    int i = b * 256 + threadIdx.x;
    int v = (i < Ntot) ? count[i] : 0;
    int lane = threadIdx.x & 63;
    int wid = threadIdx.x >> 6;
    int x = v;
#pragma unroll
    for (int s = 1; s < 64; s <<= 1) {
        int y = __shfl_up(x, s, 64);
        if (lane >= s) x += y;
    }
    if (lane == 63) ws_s[wid] = x;
    __syncthreads();
    int add = 0;
    for (int w = 0; w < wid; w++) add += ws_s[w];
    int incl = x + add;
    if (i < Ntot) base[i] = incl - v;
    if (threadIdx.x == 255) bsum[b] = incl;
}

// chunked single-block exclusive scan (any nb)
__global__ void scan2_kernel(int* __restrict__ bsum, int nb) {
    __shared__ int ws_s[4];
    __shared__ int running_s;
    if (threadIdx.x == 0) running_s = 0;
    __syncthreads();
    int lane = threadIdx.x & 63;
    int wid = threadIdx.x >> 6;
    for (int c0 = 0; c0 < nb; c0 += 256) {
        int i = c0 + threadIdx.x;
        int v = (i < nb) ? bsum[i] : 0;
        int x = v;
#pragma unroll
        for (int s = 1; s < 64; s <<= 1) {
            int y = __shfl_up(x, s, 64);
            if (lane >= s) x += y;
        }
        if (lane == 63) ws_s[wid] = x;
        __syncthreads();
        int add = 0;
        for (int w = 0; w < wid; w++) add += ws_s[w];
        int incl = x + add;
        int run = running_s;
        if (i < nb) bsum[i] = run + incl - v;
        __syncthreads();
        if (threadIdx.x == 255) running_s = run + incl;
        __syncthreads();
    }
}

// ---------- fc via MFMA, both layers in one grid ----------
#define HKPAD 136
__global__ void __launch_bounds__(256, 4)
fc_kernel(const float* __restrict__ h, const ushort* __restrict__ wbt,
          const float* __restrict__ al0, const float* __restrict__ ar0,
          const float* __restrict__ al1, const float* __restrict__ ar1,
          ushort* __restrict__ featb, float* __restrict__ el,
          float* __restrict__ er, int N, int nb) {
    __shared__ ushort hs[64 * HKPAD];
    int b = blockIdx.x;
    int l = (b >= nb);
    int n0 = (b - l * nb) * 64;
    for (int t = threadIdx.x; t < 64 * 32; t += 256) {
        int r = t >> 5, i4 = t & 31;
        int n = n0 + r;
        float4 v = make_float4(0.f, 0.f, 0.f, 0.f);
        if (n < N) v = ((const float4*)h)[(size_t)n * 32 + i4];
        uint2 pk;
        pk.x = bf16pack(v.x, v.y);
        pk.y = bf16pack(v.z, v.w);
        *((uint2*)(hs + r * HKPAD + i4 * 4)) = pk;
    }
    __syncthreads();

    const ushort* wb = wbt + l * 32768;
    const float* al = l ? al1 : al0;
    const float* ar = l ? ar1 : ar0;
    ushort* fb = featb + (size_t)l * N * 256;
    float* elp = el + (size_t)l * N * 8;
    float* erp = er + (size_t)l * N * 8;

    int wv = threadIdx.x >> 6;
    int lane = threadIdx.x & 63;
    int lhi = lane >> 4, llo = lane & 15;

    f32x4 acc[4][4];   // [cb][rt]
#pragma unroll
    for (int cb = 0; cb < 4; cb++)
#pragma unroll
        for (int rt = 0; rt < 4; rt++) acc[cb][rt] = (f32x4){0.f, 0.f, 0.f, 0.f};

#pragma unroll
    for (int ks = 0; ks < 4; ks++) {
        bf16x8 a[4];
#pragma unroll
        for (int rt = 0; rt < 4; rt++)
            a[rt] = *(const bf16x8*)(hs + (rt * 16 + llo) * HKPAD + ks * 32 + lhi * 8);
#pragma unroll
        for (int cb = 0; cb < 4; cb++) {
            bf16x8 bfrag = *(const bf16x8*)(wb + (size_t)(64 * wv + 16 * cb + llo) * 128 + ks * 32 + lhi * 8);
#pragma unroll
            for (int rt = 0; rt < 4; rt++)
                acc[cb][rt] = __builtin_amdgcn_mfma_f32_16x16x32_bf16(a[rt], bfrag, acc[cb][rt], 0, 0, 0);
        }
    }

    float alv0 = al[64 * wv + llo],      alv1 = al[64 * wv + 16 + llo];
    float alv2 = al[64 * wv + 32 + llo], alv3 = al[64 * wv + 48 + llo];
    float arv0 = ar[64 * wv + llo],      arv1 = ar[64 * wv + 16 + llo];
    float arv2 = ar[64 * wv + 32 + llo], arv3 = ar[64 * wv + 48 + llo];

#pragma unroll
    for (int rt = 0; rt < 4; rt++) {
#pragma unroll
        for (int reg = 0; reg < 4; reg++) {
            int n = n0 + rt * 16 + lhi * 4 + reg;
            bool valid = (n < N);
            uint2 pv;
            pv.x = bf16pack(acc[0][rt][reg], acc[1][rt][reg]);
            pv.y = bf16pack(acc[2][rt][reg], acc[3][rt][reg]);
            if (valid) *((uint2*)(fb + (size_t)n * 256 + 64 * wv + 4 * llo)) = pv;
            float pl0 = acc[0][rt][reg] * alv0 + acc[1][rt][reg] * alv1;
            float pl1 = acc[2][rt][reg] * alv2 + acc[3][rt][reg] * alv3;
            float pr0 = acc[0][rt][reg] * arv0 + acc[1][rt][reg] * arv1;
            float pr1 = acc[2][rt][reg] * arv2 + acc[3][rt][reg] * arv3;
#pragma unroll
            for (int s = 1; s <= 8; s <<= 1) {
                pl0 += __shfl_xor(pl0, s, 64);
                pl1 += __shfl_xor(pl1, s, 64);
                pr0 += __shfl_xor(pr0, s, 64);
                pr1 += __shfl_xor(pr1, s, 64);
            }
            if (llo == 0 && valid) {
                *((float2*)(elp + (size_t)n * 8 + 2 * wv)) = make_float2(pl0, pl1);
                *((float2*)(erp + (size_t)n * 8 + 2 * wv)) = make_float2(pr0, pr1);
            }
        }
    }
}

// ---------- scatter: build csr_src only ----------
__global__ void scatter_kernel(const int* __restrict__ e0, const int* __restrict__ e1,
                               const int* __restrict__ base, const int* __restrict__ bsum,
                               int* __restrict__ cursor, int* __restrict__ csr_src,
                               int E, int N) {
    int e = blockIdx.x * blockDim.x + threadIdx.x;
    if (e >= 2 * E) return;
    int l = (e >= E);
    int ee = e - l * E;
    const int* edges = l ? e1 : e0;
    int src = edges[ee];
    int dst = edges[E + ee];
    int d = dst + l * N;
    int pos = base[d] + bsum[d >> 8] + atomicAdd(&cursor[d], 1);
    csr_src[pos] = src;
}

// ---------- aggregate: 2 waves per dst (col halves), p computed in-kernel ----------
// wave gw: d = gw>>1 (0..2N-1), half = gw&1. Lane covers uint = 2 cols (same head).
__global__ void aggregate_csr_kernel(const int* __restrict__ csr_src, const float* __restrict__ el,
                                     const float* __restrict__ er, const int* __restrict__ base,
                                     const int* __restrict__ bsum, const int* __restrict__ count,
                                     const ushort* __restrict__ featb,
                                     const float* __restrict__ bias0, const float* __restrict__ bias1,
                                     ushort* __restrict__ z0b, ushort* __restrict__ z1b, int N) {
    int wid = threadIdx.x >> 6;
    int lane = threadIdx.x & 63;
    int gw = blockIdx.x * 4 + wid;
    if (gw >= 4 * N) return;           // 2N dsts x 2 halves
    int d = gw >> 1, half = gw & 1;
    int l = (d >= N);
    int dst = d - l * N;
    int row0 = base[d] + bsum[d >> 8];
    int deg = count[d];
    // head of this lane's uint (both bf16 share it)
    int hh = 4 * half + ((lane >> 5) << 1) + (lane & 1);
    int p0 = half * 128 + 2 * lane;
    int p1 = p0 + 1;
    int c0 = 64 * (p0 >> 6) + 16 * (p0 & 3) + ((p0 >> 2) & 15);
    int c1 = 64 * (p1 >> 6) + 16 * (p1 & 3) + ((p1 >> 2) & 15);

    const float* elb = el + (size_t)l * N * 8;
    float erv = er[((size_t)l * N + dst) * 8 + hh];
    const uint* fbu = ((const uint*)featb) + (size_t)l * N * 128;
    const int* cs = csr_src + row0;
    int lo = half * 64 + lane;

    float dacc = 0.f, a0 = 0.f, a1 = 0.f;
    int t = 0;
    for (; t + 4 <= deg; t += 4) {
        int s0 = __builtin_amdgcn_readfirstlane(cs[t]);
        int s1 = __builtin_amdgcn_readfirstlane(cs[t + 1]);
        int s2 = __builtin_amdgcn_readfirstlane(cs[t + 2]);
        int s3 = __builtin_amdgcn_readfirstlane(cs[t + 3]);
        float x0 = elb[(size_t)s0 * 8 + hh] + erv;
        float x1 = elb[(size_t)s1 * 8 + hh] + erv;
        float x2 = elb[(size_t)s2 * 8 + hh] + erv;
        float x3 = elb[(size_t)s3 * 8 + hh] + erv;
        uint u0 = fbu[(size_t)s0 * 128 + lo];
        uint u1 = fbu[(size_t)s1 * 128 + lo];
        uint u2 = fbu[(size_t)s2 * 128 + lo];
        uint u3 = fbu[(size_t)s3 * 128 + lo];
        x0 = (x0 > 0.f) ? x0 : NEG_SLOPE * x0;  float q0 = __expf(x0);
        x1 = (x1 > 0.f) ? x1 : NEG_SLOPE * x1;  float q1 = __expf(x1);
        x2 = (x2 > 0.f) ? x2 : NEG_SLOPE * x2;  float q2 = __expf(x2);
        x3 = (x3 > 0.f) ? x3 : NEG_SLOPE * x3;  float q3 = __expf(x3);
        dacc += q0; a0 += q0 * bflo(u0); a1 += q0 * bfhi(u0);
        dacc += q1; a0 += q1 * bflo(u1); a1 += q1 * bfhi(u1);
        dacc += q2; a0 += q2 * bflo(u2); a1 += q2 * bfhi(u2);
        dacc += q3; a0 += q3 * bflo(u3); a1 += q3 * bfhi(u3);
    }
    for (; t < deg; t++) {
        int s0 = __builtin_amdgcn_readfirstlane(cs[t]);
        float x0 = elb[(size_t)s0 * 8 + hh] + erv;
        uint u0 = fbu[(size_t)s0 * 128 + lo];
        x0 = (x0 > 0.f) ? x0 : NEG_SLOPE * x0;  float q0 = __expf(x0);
        dacc += q0; a0 += q0 * bflo(u0); a1 += q0 * bfhi(u0);
    }
    const float* bias = l ? bias1 : bias0;
    float inv = (dacc > 0.f) ? 1.f / dacc : 0.f;
    uint o = bf16pack(a0 * inv + bias[c0], a1 * inv + bias[c1]);
    uint* zb = (uint*)(l ? z1b : z0b);
    zb[(size_t)dst * 128 + lo] = o;
}

// ---------- semantic attention via MFMA, B-reuse ----------
#define ZROW 264
__global__ void __launch_bounds__(256, 4)
semantic_kernel(const ushort* __restrict__ z0b, const ushort* __restrict__ z1b,
                const ushort* __restrict__ sw1t, const float* __restrict__ sb1,
                const float* __restrict__ sw2, float* __restrict__ wsum, int N) {
    __shared__ ushort zs[64 * ZROW];
    __shared__ float rowp[64];
    int n0 = blockIdx.x * 32;
    if (threadIdx.x < 64) rowp[threadIdx.x] = 0.f;
    for (int t = threadIdx.x; t < 64 * 32; t += 256) {
        int row = t >> 5, i16 = t & 31;
        int r = row >> 1, mm = row & 1;
        int n = n0 + r;
        uint4 v = make_uint4(0u, 0u, 0u, 0u);
        if (n < N) v = ((const uint4*)(mm ? z1b : z0b))[(size_t)n * 32 + i16];
        *((uint4*)(zs + row * ZROW + i16 * 8)) = v;
    }
    __syncthreads();

    int wv = threadIdx.x >> 6;
    int lane = threadIdx.x & 63;
    int lhi = lane >> 4, llo = lane & 15;

    f32x4 acc[2][4];
#pragma unroll
    for (int c = 0; c < 2; c++)
#pragma unroll
        for (int rt = 0; rt < 4; rt++) acc[c][rt] = (f32x4){0.f, 0.f, 0.f, 0.f};

#pragma unroll
    for (int ks = 0; ks < 8; ks++) {
        bf16x8 b0 = *(const bf16x8*)(sw1t + (size_t)((2 * wv) * 16 + llo) * 256 + ks * 32 + lhi * 8);
        bf16x8 b1 = *(const bf16x8*)(sw1t + (size_t)((2 * wv + 1) * 16 + llo) * 256 + ks * 32 + lhi * 8);
#pragma unroll
        for (int rt = 0; rt < 4; rt++) {
            bf16x8 av = *(const bf16x8*)(zs + (rt * 16 + llo) * ZROW + ks * 32 + lhi * 8);
            acc[0][rt] = __builtin_amdgcn_mfma_f32_16x16x32_bf16(av, b0, acc[0][rt], 0, 0, 0);
            acc[1][rt] = __builtin_amdgcn_mfma_f32_16x16x32_bf16(av, b1, acc[1][rt], 0, 0, 0);
        }
    }

    float sb0 = sb1[(2 * wv) * 16 + llo],      s20 = sw2[(2 * wv) * 16 + llo];
    float sb1v = sb1[(2 * wv + 1) * 16 + llo], s21 = sw2[(2 * wv + 1) * 16 + llo];
#pragma unroll
    for (int rt = 0; rt < 4; rt++) {
        float pr[4];
#pragma unroll
        for (int reg = 0; reg < 4; reg++)
            pr[reg] = tanhf(acc[0][rt][reg] + sb0) * s20 + tanhf(acc[1][rt][reg] + sb1v) * s21;
#pragma unroll
        for (int s = 1; s <= 8; s <<= 1)
#pragma unroll
            for (int reg = 0; reg < 4; reg++) pr[reg] += __shfl_xor(pr[reg], s, 64);
        if (llo == 0) {
#pragma unroll
            for (int reg = 0; reg < 4; reg++)
                atomicAdd(&rowp[rt * 16 + lhi * 4 + reg], pr[reg]);
        }
    }
    __syncthreads();
    if (threadIdx.x < 64) {
        int node = n0 + (threadIdx.x >> 1);
        float v = (node < N) ? rowp[threadIdx.x] : 0.f;
        v += __shfl_xor(v, 2, 64);
        v += __shfl_xor(v, 4, 64);
        v += __shfl_xor(v, 8, 64);
        v += __shfl_xor(v, 16, 64);
        v += __shfl_xor(v, 32, 64);
        if (threadIdx.x < 2) atomicAdd(&wsum[threadIdx.x], v);
    }
}

// ---------- combine (inline beta): out(f32, unpermuted) ----------
__global__ void combine_kernel(float* __restrict__ out, const ushort* __restrict__ z0b,
                               const ushort* __restrict__ z1b, const float* __restrict__ wsum,
                               float invN, int N) {
    int idx = blockIdx.x * 256 + threadIdx.x;
    if (idx >= N * 64) return;
    float w0 = wsum[0] * invN, w1 = wsum[1] * invN;
    float mx = fmaxf(w0, w1);
    float e0 = __expf(w0 - mx), e1 = __expf(w1 - mx);
    float b0 = e0 / (e0 + e1), b1 = e1 / (e0 + e1);
    int n = idx >> 6, lane = idx & 63;
    int w = lane >> 4, llo = lane & 15;
    uint2 a = ((const uint2*)z0b)[idx];
    uint2 b = ((const uint2*)z1b)[idx];
    float* o = out + (size_t)n * 256 + 64 * w + llo;
    o[0]  = b0 * bflo(a.x) + b1 * bflo(b.x);
    o[16] = b0 * bfhi(a.x) + b1 * bfhi(b.x);
    o[32] = b0 * bflo(a.y) + b1 * bflo(b.y);
    o[48] = b0 * bfhi(a.y) + b1 * bfhi(b.y);
}

extern "C" void kernel_launch(void* const* d_in, const int* in_sizes, int n_in,
                              void* d_out, int out_size, void* d_ws, size_t ws_size,
                              hipStream_t stream) {
    const float* h      = (const float*)d_in[0];
    const int*   edges0 = (const int*)d_in[1];
    const int*   edges1 = (const int*)d_in[2];
    const float* fc0    = (const float*)d_in[3];
    const float* al0    = (const float*)d_in[4];
    const float* ar0    = (const float*)d_in[5];
    const float* bias0  = (const float*)d_in[6];
    const float* fc1    = (const float*)d_in[7];
    const float* al1    = (const float*)d_in[8];
    const float* ar1    = (const float*)d_in[9];
    const float* bias1  = (const float*)d_in[10];
    const float* sw1    = (const float*)d_in[11];
    const float* sb1    = (const float*)d_in[12];
    const float* sw2    = (const float*)d_in[13];

    const int N = in_sizes[0] / 128;
    const int E = in_sizes[1] / 2;
    const int Ntot = 2 * N;
    const int NB2 = (Ntot + 255) / 256;
    const int nb = (N + 63) / 64;

    char* ws = (char*)d_ws;
    ushort* featb = (ushort*)ws;                       // 2N*256 bf16 (perm, per layer)
    ushort* z0b   = featb + (size_t)Ntot * 256;        // N*256
    ushort* z1b   = z0b + (size_t)N * 256;             // N*256
    ushort* wbt   = z1b + (size_t)N * 256;             // 2*256*128
    ushort* sw1t  = wbt + 2 * 256 * 128;               // 128*256
    float*  el    = (float*)(sw1t + 128 * 256);        // 2N*8
    float*  er    = el + (size_t)Ntot * 8;             // 2N*8
    int*    csr_src = (int*)(er + (size_t)Ntot * 8);   // 2E
    int*    count   = csr_src + 2 * E;                 // 2N
    int*    base    = count + Ntot;                    // 2N
    int*    cursor  = base + Ntot;                     // 2N
    int*    bsum    = cursor + Ntot;                   // NB2
    float*  wsum  = (float*)(bsum + NB2 + 2);          // 2
    float*  outp  = (float*)d_out;                     // N*256 f32

    prep_kernel<<<384 + NB2, 256, 0, stream>>>(fc0, fc1, sw1, wbt, sw1t, wsum,
                                               count, cursor, Ntot);
    hist_kernel<<<(2 * E + 255) / 256, 256, 0, stream>>>(edges0, edges1, count, E, N);
    scan1_kernel<<<NB2, 256, 0, stream>>>(count, base, bsum, Ntot);
    scan2_kernel<<<1, 256, 0, stream>>>(bsum, NB2);
    fc_kernel<<<2 * nb, 256, 0, stream>>>(h, wbt, al0, ar0, al1, ar1, featb, el, er, N, nb);
    scatter_kernel<<<(2 * E + 255) / 256, 256, 0, stream>>>(edges0, edges1, base, bsum,
                                                            cursor, csr_src, E, N);
    aggregate_csr_kernel<<<N, 256, 0, stream>>>(csr_src, el, er, base, bsum, count,
                                                featb, bias0, bias1, z0b, z1b, N);
    semantic_kernel<<<(N + 31) / 32, 256, 0, stream>>>(z0b, z1b, sw1t, sb1, sw2, wsum, N);
    combine_kernel<<<(N * 64 + 255) / 256, 256, 0, stream>>>(outp, z0b, z1b, wsum,
                                                             1.0f / (float)N, N);
}

// Round 9
// 260.200 us; speedup vs baseline: 1.1049x; 1.1049x over previous
//
#include <hip/hip_runtime.h>
#include <math.h>

#define NEG_SLOPE 0.2f

typedef unsigned int uint;
typedef unsigned short ushort;
typedef __bf16 bf16x8 __attribute__((ext_vector_type(8)));
typedef float f32x4 __attribute__((ext_vector_type(4)));

__device__ __forceinline__ uint bf16r(float a) {
    uint u = __float_as_uint(a);
    return (u + 0x7fffu + ((u >> 16) & 1u)) >> 16;
}
__device__ __forceinline__ uint bf16pack(float a, float b) {
    return bf16r(a) | (bf16r(b) << 16);
}
__device__ __forceinline__ float bflo(uint u) { return __uint_as_float(u << 16); }
__device__ __forceinline__ float bfhi(uint u) { return __uint_as_float(u & 0xffff0000u); }

// ---------- prep: wbt, sw1t(perm), wsum=0, count/cursor=0 ----------
__global__ void prep_kernel(const float* __restrict__ fc0, const float* __restrict__ fc1,
                            const float* __restrict__ sw1, ushort* __restrict__ wbt,
                            ushort* __restrict__ sw1t, float* __restrict__ wsum,
                            int* __restrict__ count, int* __restrict__ cursor, int Ntot) {
    int b = blockIdx.x;
    if (b == 0 && threadIdx.x == 0) { wsum[0] = 0.f; wsum[1] = 0.f; }
    if (b < 256) {
        int idx = b * 256 + threadIdx.x;            // 65536
        const float* W = (idx >> 15) ? fc1 : fc0;
        int r = idx & 32767;
        int c = r >> 7, k = r & 127;
        wbt[idx] = (ushort)bf16r(W[(size_t)k * 256 + c]);
    } else if (b < 384) {
        int idx = (b - 256) * 256 + threadIdx.x;    // 32768
        int c = idx >> 8, p = idx & 255;
        int col = (p & ~63) + ((p & 3) * 16) + ((p >> 2) & 15);
        sw1t[idx] = (ushort)bf16r(sw1[(size_t)col * 128 + c]);
    } else {
        int i = (b - 384) * 256 + threadIdx.x;
        if (i < Ntot) { count[i] = 0; cursor[i] = 0; }
    }
}

// ---------- hist over both layers: d' = dst + l*N ----------
__global__ void hist_kernel(const int* __restrict__ e0, const int* __restrict__ e1,
                            int* __restrict__ count, int E, int N) {
    int e = blockIdx.x * blockDim.x + threadIdx.x;
    if (e >= 2 * E) return;
    int l = (e >= E);
    int ee = e - l * E;
    const int* edges = l ? e1 : e0;
    atomicAdd(&count[edges[E + ee] + l * N], 1);
}

__global__ void scan1_kernel(const int* __restrict__ count, int* __restrict__ base,
                             int* __restrict__ bsum, int Ntot) {
    __shared__ int ws_s[4];
    int b = blockIdx.x;
    int i = b * 256 + threadIdx.x;
    int v = (i < Ntot) ? count[i] : 0;
    int lane = threadIdx.x & 63;
    int wid = threadIdx.x >> 6;
    int x = v;
#pragma unroll
    for (int s = 1; s < 64; s <<= 1) {
        int y = __shfl_up(x, s, 64);
        if (lane >= s) x += y;
    }
    if (lane == 63) ws_s[wid] = x;
    __syncthreads();
    int add = 0;
    for (int w = 0; w < wid; w++) add += ws_s[w];
    int incl = x + add;
    if (i < Ntot) base[i] = incl - v;
    if (threadIdx.x == 255) bsum[b] = incl;
}

// chunked single-block exclusive scan (any nb)
__global__ void scan2_kernel(int* __restrict__ bsum, int nb) {
    __shared__ int ws_s[4];
    __shared__ int running_s;
    if (threadIdx.x == 0) running_s = 0;
    __syncthreads();
    int lane = threadIdx.x & 63;
    int wid = threadIdx.x >> 6;
    for (int c0 = 0; c0 < nb; c0 += 256) {
        int i = c0 + threadIdx.x;
        int v = (i < nb) ? bsum[i] : 0;
        int x = v;
#pragma unroll
        for (int s = 1; s < 64; s <<= 1) {
            int y = __shfl_up(x, s, 64);
            if (lane >= s) x += y;
        }
        if (lane == 63) ws_s[wid] = x;
        __syncthreads();
        int add = 0;
        for (int w = 0; w < wid; w++) add += ws_s[w];
        int incl = x + add;
        int run = running_s;
        if (i < nb) bsum[i] = run + incl - v;
        __syncthreads();
        if (threadIdx.x == 255) running_s = run + incl;
        __syncthreads();
    }
}

// ---------- fc via MFMA, both layers in one grid ----------
#define HKPAD 136
__global__ void __launch_bounds__(256, 4)
fc_kernel(const float* __restrict__ h, const ushort* __restrict__ wbt,
          const float* __restrict__ al0, const float* __restrict__ ar0,
          const float* __restrict__ al1, const float* __restrict__ ar1,
          ushort* __restrict__ featb, float* __restrict__ el,
          float* __restrict__ er, int N, int nb) {
    __shared__ ushort hs[64 * HKPAD];
    int b = blockIdx.x;
    int l = (b >= nb);
    int n0 = (b - l * nb) * 64;
    for (int t = threadIdx.x; t < 64 * 32; t += 256) {
        int r = t >> 5, i4 = t & 31;
        int n = n0 + r;
        float4 v = make_float4(0.f, 0.f, 0.f, 0.f);
        if (n < N) v = ((const float4*)h)[(size_t)n * 32 + i4];
        uint2 pk;
        pk.x = bf16pack(v.x, v.y);
        pk.y = bf16pack(v.z, v.w);
        *((uint2*)(hs + r * HKPAD + i4 * 4)) = pk;
    }
    __syncthreads();

    const ushort* wb = wbt + l * 32768;
    const float* al = l ? al1 : al0;
    const float* ar = l ? ar1 : ar0;
    ushort* fb = featb + (size_t)l * N * 256;
    float* elp = el + (size_t)l * N * 8;
    float* erp = er + (size_t)l * N * 8;

    int wv = threadIdx.x >> 6;
    int lane = threadIdx.x & 63;
    int lhi = lane >> 4, llo = lane & 15;

    f32x4 acc[4][4];   // [cb][rt]
#pragma unroll
    for (int cb = 0; cb < 4; cb++)
#pragma unroll
        for (int rt = 0; rt < 4; rt++) acc[cb][rt] = (f32x4){0.f, 0.f, 0.f, 0.f};

#pragma unroll
    for (int ks = 0; ks < 4; ks++) {
        bf16x8 a[4];
#pragma unroll
        for (int rt = 0; rt < 4; rt++)
            a[rt] = *(const bf16x8*)(hs + (rt * 16 + llo) * HKPAD + ks * 32 + lhi * 8);
#pragma unroll
        for (int cb = 0; cb < 4; cb++) {
            bf16x8 bfrag = *(const bf16x8*)(wb + (size_t)(64 * wv + 16 * cb + llo) * 128 + ks * 32 + lhi * 8);
#pragma unroll
            for (int rt = 0; rt < 4; rt++)
                acc[cb][rt] = __builtin_amdgcn_mfma_f32_16x16x32_bf16(a[rt], bfrag, acc[cb][rt], 0, 0, 0);
        }
    }

    float alv0 = al[64 * wv + llo],      alv1 = al[64 * wv + 16 + llo];
    float alv2 = al[64 * wv + 32 + llo], alv3 = al[64 * wv + 48 + llo];
    float arv0 = ar[64 * wv + llo],      arv1 = ar[64 * wv + 16 + llo];
    float arv2 = ar[64 * wv + 32 + llo], arv3 = ar[64 * wv + 48 + llo];

#pragma unroll
    for (int rt = 0; rt < 4; rt++) {
#pragma unroll
        for (int reg = 0; reg < 4; reg++) {
            int n = n0 + rt * 16 + lhi * 4 + reg;
            bool valid = (n < N);
            uint2 pv;
            pv.x = bf16pack(acc[0][rt][reg], acc[1][rt][reg]);
            pv.y = bf16pack(acc[2][rt][reg], acc[3][rt][reg]);
            if (valid) *((uint2*)(fb + (size_t)n * 256 + 64 * wv + 4 * llo)) = pv;
            float pl0 = acc[0][rt][reg] * alv0 + acc[1][rt][reg] * alv1;
            float pl1 = acc[2][rt][reg] * alv2 + acc[3][rt][reg] * alv3;
            float pr0 = acc[0][rt][reg] * arv0 + acc[1][rt][reg] * arv1;
            float pr1 = acc[2][rt][reg] * arv2 + acc[3][rt][reg] * arv3;
#pragma unroll
            for (int s = 1; s <= 8; s <<= 1) {
                pl0 += __shfl_xor(pl0, s, 64);
                pl1 += __shfl_xor(pl1, s, 64);
                pr0 += __shfl_xor(pr0, s, 64);
                pr1 += __shfl_xor(pr1, s, 64);
            }
            if (llo == 0 && valid) {
                *((float2*)(elp + (size_t)n * 8 + 2 * wv)) = make_float2(pl0, pl1);
                *((float2*)(erp + (size_t)n * 8 + 2 * wv)) = make_float2(pr0, pr1);
            }
        }
    }
}

// ---------- scatter: csr_src + pre-exponentiated logits (round-7 form) ----------
__global__ void scatter_kernel(const int* __restrict__ e0, const int* __restrict__ e1,
                               const float* __restrict__ el, const float* __restrict__ er,
                               const int* __restrict__ base, const int* __restrict__ bsum,
                               int* __restrict__ cursor, int* __restrict__ csr_src,
                               float* __restrict__ pedge, int E, int N) {
    int e = blockIdx.x * blockDim.x + threadIdx.x;
    if (e >= 2 * E) return;
    int l = (e >= E);
    int ee = e - l * E;
    const int* edges = l ? e1 : e0;
    int src = edges[ee];
    int dst = edges[E + ee];
    int d = dst + l * N;
    int pos = base[d] + bsum[d >> 8] + atomicAdd(&cursor[d], 1);
    csr_src[pos] = src;
    size_t so = (size_t)(l * N + src) * 2;
    size_t dofs = (size_t)(l * N + dst) * 2;
    float4 l0 = ((const float4*)el)[so];
    float4 l1 = ((const float4*)el)[so + 1];
    float4 r0 = ((const float4*)er)[dofs];
    float4 r1 = ((const float4*)er)[dofs + 1];
    float v[8] = {l0.x + r0.x, l0.y + r0.y, l0.z + r0.z, l0.w + r0.w,
                  l1.x + r1.x, l1.y + r1.y, l1.z + r1.z, l1.w + r1.w};
#pragma unroll
    for (int k = 0; k < 8; k++) {
        float t = (v[k] > 0.f) ? v[k] : NEG_SLOPE * v[k];
        v[k] = __expf(t);    // softmax shift-invariant; logits O(1)
    }
    ((float4*)pedge)[pos * 2]     = make_float4(v[0], v[1], v[2], v[3]);
    ((float4*)pedge)[pos * 2 + 1] = make_float4(v[4], v[5], v[6], v[7]);
}

// ---------- aggregate (round-7 form): one wave per d', 4-wide unrolled gathers ----------
__global__ void aggregate_csr_kernel(const int* __restrict__ csr_src, const float* __restrict__ pedge,
                                     const int* __restrict__ base, const int* __restrict__ bsum,
                                     const int* __restrict__ count, const ushort* __restrict__ featb,
                                     const float* __restrict__ bias0, const float* __restrict__ bias1,
                                     ushort* __restrict__ z0b, ushort* __restrict__ z1b, int N) {
    int wid = threadIdx.x >> 6;
    int lane = threadIdx.x & 63;
    int d = blockIdx.x * 4 + wid;
    if (d >= 2 * N) return;
    int l = (d >= N);
    int dst = d - l * N;
    int row0 = base[d] + bsum[d >> 8];
    int deg = count[d];
    int w = lane >> 4, llo = lane & 15;
    const ushort* fb = featb + (size_t)l * N * 256;
    const float2* pe = (const float2*)(pedge + (size_t)row0 * 8);
    const int* cs = csr_src + row0;
    const uint2* fb2 = (const uint2*)fb;

    float d0 = 0.f, d1 = 0.f;
    float4 a = make_float4(0.f, 0.f, 0.f, 0.f);
    int t = 0;
    for (; t + 4 <= deg; t += 4) {
        int s0 = cs[t], s1 = cs[t + 1], s2 = cs[t + 2], s3 = cs[t + 3];
        float2 q0 = pe[t * 4 + w];
        float2 q1 = pe[t * 4 + 4 + w];
        float2 q2 = pe[t * 4 + 8 + w];
        float2 q3 = pe[t * 4 + 12 + w];
        uint2 u0 = fb2[(size_t)s0 * 64 + lane];
        uint2 u1 = fb2[(size_t)s1 * 64 + lane];
        uint2 u2 = fb2[(size_t)s2 * 64 + lane];
        uint2 u3 = fb2[(size_t)s3 * 64 + lane];
        d0 += q0.x; d1 += q0.y;
        a.x += q0.x * bflo(u0.x); a.y += q0.x * bfhi(u0.x);
        a.z += q0.y * bflo(u0.y); a.w += q0.y * bfhi(u0.y);
        d0 += q1.x; d1 += q1.y;
        a.x += q1.x * bflo(u1.x); a.y += q1.x * bfhi(u1.x);
        a.z += q1.y * bflo(u1.y); a.w += q1.y * bfhi(u1.y);
        d0 += q2.x; d1 += q2.y;
        a.x += q2.x * bflo(u2.x); a.y += q2.x * bfhi(u2.x);
        a.z += q2.y * bflo(u2.y); a.w += q2.y * bfhi(u2.y);
        d0 += q3.x; d1 += q3.y;
        a.x += q3.x * bflo(u3.x); a.y += q3.x * bfhi(u3.x);
        a.z += q3.y * bflo(u3.y); a.w += q3.y * bfhi(u3.y);
    }
    for (; t < deg; t++) {
        int s0 = cs[t];
        float2 q0 = pe[t * 4 + w];
        uint2 u0 = fb2[(size_t)s0 * 64 + lane];
        d0 += q0.x; d1 += q0.y;
        a.x += q0.x * bflo(u0.x); a.y += q0.x * bfhi(u0.x);
        a.z += q0.y * bflo(u0.y); a.w += q0.y * bfhi(u0.y);
    }
    const float* bias = l ? bias1 : bias0;
    int c0 = 64 * w + llo;
    float b0 = bias[c0], b1 = bias[c0 + 16], b2 = bias[c0 + 32], b3 = bias[c0 + 48];
    float i0 = (d0 > 0.f) ? 1.f / d0 : 0.f;
    float i1 = (d1 > 0.f) ? 1.f / d1 : 0.f;
    uint2 o;
    o.x = bf16pack(a.x * i0 + b0, a.y * i0 + b1);
    o.y = bf16pack(a.z * i1 + b2, a.w * i1 + b3);
    ushort* zb = l ? z1b : z0b;
    ((uint2*)zb)[(size_t)dst * 64 + lane] = o;
}

// ---------- semantic attention via MFMA, B-reuse ----------
#define ZROW 264
__global__ void __launch_bounds__(256, 4)
semantic_kernel(const ushort* __restrict__ z0b, const ushort* __restrict__ z1b,
                const ushort* __restrict__ sw1t, const float* __restrict__ sb1,
                const float* __restrict__ sw2, float* __restrict__ wsum, int N) {
    __shared__ ushort zs[64 * ZROW];
    __shared__ float rowp[64];
    int n0 = blockIdx.x * 32;
    if (threadIdx.x < 64) rowp[threadIdx.x] = 0.f;
    for (int t = threadIdx.x; t < 64 * 32; t += 256) {
        int row = t >> 5, i16 = t & 31;
        int r = row >> 1, mm = row & 1;
        int n = n0 + r;
        uint4 v = make_uint4(0u, 0u, 0u, 0u);
        if (n < N) v = ((const uint4*)(mm ? z1b : z0b))[(size_t)n * 32 + i16];
        *((uint4*)(zs + row * ZROW + i16 * 8)) = v;
    }
    __syncthreads();

    int wv = threadIdx.x >> 6;
    int lane = threadIdx.x & 63;
    int lhi = lane >> 4, llo = lane & 15;

    f32x4 acc[2][4];
#pragma unroll
    for (int c = 0; c < 2; c++)
#pragma unroll
        for (int rt = 0; rt < 4; rt++) acc[c][rt] = (f32x4){0.f, 0.f, 0.f, 0.f};

#pragma unroll
    for (int ks = 0; ks < 8; ks++) {
        bf16x8 b0 = *(const bf16x8*)(sw1t + (size_t)((2 * wv) * 16 + llo) * 256 + ks * 32 + lhi * 8);
        bf16x8 b1 = *(const bf16x8*)(sw1t + (size_t)((2 * wv + 1) * 16 + llo) * 256 + ks * 32 + lhi * 8);
#pragma unroll
        for (int rt = 0; rt < 4; rt++) {
            bf16x8 av = *(const bf16x8*)(zs + (rt * 16 + llo) * ZROW + ks * 32 + lhi * 8);
            acc[0][rt] = __builtin_amdgcn_mfma_f32_16x16x32_bf16(av, b0, acc[0][rt], 0, 0, 0);
            acc[1][rt] = __builtin_amdgcn_mfma_f32_16x16x32_bf16(av, b1, acc[1][rt], 0, 0, 0);
        }
    }

    float sb0 = sb1[(2 * wv) * 16 + llo],      s20 = sw2[(2 * wv) * 16 + llo];
    float sb1v = sb1[(2 * wv + 1) * 16 + llo], s21 = sw2[(2 * wv + 1) * 16 + llo];
#pragma unroll
    for (int rt = 0; rt < 4; rt++) {
        float pr[4];
#pragma unroll
        for (int reg = 0; reg < 4; reg++)
            pr[reg] = tanhf(acc[0][rt][reg] + sb0) * s20 + tanhf(acc[1][rt][reg] + sb1v) * s21;
#pragma unroll
        for (int s = 1; s <= 8; s <<= 1)
#pragma unroll
            for (int reg = 0; reg < 4; reg++) pr[reg] += __shfl_xor(pr[reg], s, 64);
        if (llo == 0) {
#pragma unroll
            for (int reg = 0; reg < 4; reg++)
                atomicAdd(&rowp[rt * 16 + lhi * 4 + reg], pr[reg]);
        }
    }
    __syncthreads();
    if (threadIdx.x < 64) {
        int node = n0 + (threadIdx.x >> 1);
        float v = (node < N) ? rowp[threadIdx.x] : 0.f;
        v += __shfl_xor(v, 2, 64);
        v += __shfl_xor(v, 4, 64);
        v += __shfl_xor(v, 8, 64);
        v += __shfl_xor(v, 16, 64);
        v += __shfl_xor(v, 32, 64);
        if (threadIdx.x < 2) atomicAdd(&wsum[threadIdx.x], v);
    }
}

// ---------- combine (inline beta): out(f32, unpermuted) ----------
__global__ void combine_kernel(float* __restrict__ out, const ushort* __restrict__ z0b,
                               const ushort* __restrict__ z1b, const float* __restrict__ wsum,
                               float invN, int N) {
    int idx = blockIdx.x * 256 + threadIdx.x;
    if (idx >= N * 64) return;
    float w0 = wsum[0] * invN, w1 = wsum[1] * invN;
    float mx = fmaxf(w0, w1);
    float e0 = __expf(w0 - mx), e1 = __expf(w1 - mx);
    float b0 = e0 / (e0 + e1), b1 = e1 / (e0 + e1);
    int n = idx >> 6, lane = idx & 63;
    int w = lane >> 4, llo = lane & 15;
    uint2 a = ((const uint2*)z0b)[idx];
    uint2 b = ((const uint2*)z1b)[idx];
    float* o = out + (size_t)n * 256 + 64 * w + llo;
    o[0]  = b0 * bflo(a.x) + b1 * bflo(b.x);
    o[16] = b0 * bfhi(a.x) + b1 * bfhi(b.x);
    o[32] = b0 * bflo(a.y) + b1 * bflo(b.y);
    o[48] = b0 * bfhi(a.y) + b1 * bfhi(b.y);
}

extern "C" void kernel_launch(void* const* d_in, const int* in_sizes, int n_in,
                              void* d_out, int out_size, void* d_ws, size_t ws_size,
                              hipStream_t stream) {
    const float* h      = (const float*)d_in[0];
    const int*   edges0 = (const int*)d_in[1];
    const int*   edges1 = (const int*)d_in[2];
    const float* fc0    = (const float*)d_in[3];
    const float* al0    = (const float*)d_in[4];
    const float* ar0    = (const float*)d_in[5];
    const float* bias0  = (const float*)d_in[6];
    const float* fc1    = (const float*)d_in[7];
    const float* al1    = (const float*)d_in[8];
    const float* ar1    = (const float*)d_in[9];
    const float* bias1  = (const float*)d_in[10];
    const float* sw1    = (const float*)d_in[11];
    const float* sb1    = (const float*)d_in[12];
    const float* sw2    = (const float*)d_in[13];

    const int N = in_sizes[0] / 128;
    const int E = in_sizes[1] / 2;
    const int Ntot = 2 * N;
    const int NB2 = (Ntot + 255) / 256;
    const int nb = (N + 63) / 64;

    char* ws = (char*)d_ws;
    ushort* featb = (ushort*)ws;                       // 2N*256 bf16 (perm, per layer)
    ushort* z0b   = featb + (size_t)Ntot * 256;        // N*256
    ushort* z1b   = z0b + (size_t)N * 256;             // N*256
    ushort* wbt   = z1b + (size_t)N * 256;             // 2*256*128
    ushort* sw1t  = wbt + 2 * 256 * 128;               // 128*256
    float*  el    = (float*)(sw1t + 128 * 256);        // 2N*8
    float*  er    = el + (size_t)Ntot * 8;             // 2N*8
    float*  pedge = er + (size_t)Ntot * 8;             // 2E*8
    int*    csr_src = (int*)(pedge + (size_t)E * 16);  // 2E
    int*    count   = csr_src + 2 * E;                 // 2N
    int*    base    = count + Ntot;                    // 2N
    int*    cursor  = base + Ntot;                     // 2N
    int*    bsum    = cursor + Ntot;                   // NB2
    float*  wsum  = (float*)(bsum + NB2 + 2);          // 2
    float*  outp  = (float*)d_out;                     // N*256 f32

    prep_kernel<<<384 + NB2, 256, 0, stream>>>(fc0, fc1, sw1, wbt, sw1t, wsum,
                                               count, cursor, Ntot);
    hist_kernel<<<(2 * E + 255) / 256, 256, 0, stream>>>(edges0, edges1, count, E, N);
    scan1_kernel<<<NB2, 256, 0, stream>>>(count, base, bsum, Ntot);
    scan2_kernel<<<1, 256, 0, stream>>>(bsum, NB2);
    fc_kernel<<<2 * nb, 256, 0, stream>>>(h, wbt, al0, ar0, al1, ar1, featb, el, er, N, nb);
    scatter_kernel<<<(2 * E + 255) / 256, 256, 0, stream>>>(edges0, edges1, el, er, base, bsum,
                                                            cursor, csr_src, pedge, E, N);
    aggregate_csr_kernel<<<(Ntot + 3) / 4, 256, 0, stream>>>(csr_src, pedge, base, bsum, count,
                                                             featb, bias0, bias1, z0b, z1b, N);
    semantic_kernel<<<(N + 31) / 32, 256, 0, stream>>>(z0b, z1b, sw1t, sb1, sw2, wsum, N);
    combine_kernel<<<(N * 64 + 255) / 256, 256, 0, stream>>>(outp, z0b, z1b, wsum,
                                                             1.0f / (float)N, N);
}